// Round 10
// baseline (423.617 us; speedup 1.0000x reference)
//
#include <hip/hip_runtime.h>
#include <stdint.h>

typedef _Float16 f16;
typedef _Float16 f16x4 __attribute__((ext_vector_type(4)));
typedef _Float16 f16x8 __attribute__((ext_vector_type(8)));
typedef float floatx4 __attribute__((ext_vector_type(4)));

#define B_ROWS 4096
#define D_IN   768
#define H_DIM  16384
#define TOPK_N 32
#define NCAP   256     // per-row candidate cap (mean ~117, overflow prob ~0)
#define THETA_C 0.0264565f   // 2.45 * sqrt(2/(768+16384))
#define WIN     0.04f        // exact-recompute window below approx rank-32

#define BM 256
#define BN 256
#define BK 64
#define NKT (D_IN / BK)   // 12 K-tiles

typedef __attribute__((address_space(1))) const unsigned int g_uint;
typedef __attribute__((address_space(3))) unsigned int l_uint;

__device__ __forceinline__ void gload_lds16(const void* g, void* l) {
    __builtin_amdgcn_global_load_lds((g_uint*)(uintptr_t)g,
                                     (l_uint*)(uint32_t)(uintptr_t)l,
                                     16, 0, 0);
}

// ---------------- split x -> f16, per-row theta, zero cand counters ----------------
__global__ __launch_bounds__(192) void split_x_theta(const float* __restrict__ x,
                                                     f16* __restrict__ xhi,
                                                     float* __restrict__ theta,
                                                     int* __restrict__ cntg) {
    const int row = blockIdx.x;
    const int t   = threadIdx.x;          // 0..191, one float4 each
    const float4 q = ((const float4*)(x + (size_t)row * D_IN))[t];
    f16x4 h;
    h[0] = (f16)q.x; h[1] = (f16)q.y; h[2] = (f16)q.z; h[3] = (f16)q.w;
    ((f16x4*)xhi)[(size_t)row * (D_IN / 4) + t] = h;
    float ss = q.x * q.x + q.y * q.y + q.z * q.z + q.w * q.w;
#pragma unroll
    for (int off = 32; off > 0; off >>= 1) ss += __shfl_down(ss, off);
    __shared__ float swave[3];
    if ((t & 63) == 0) swave[t >> 6] = ss;
    __syncthreads();
    if (t == 0) {
        const float tot = swave[0] + swave[1] + swave[2];
        theta[row] = THETA_C * sqrtf(tot);
        cntg[row] = 0;
    }
}

// ---------------- transpose + hi/lo split of W_enc ----------------
// W [768][16384] f32  ->  whiT/wloT [16384][768] f16 (k contiguous)
__global__ __launch_bounds__(256) void split_transpose_w(const float* __restrict__ W,
                                                         f16* __restrict__ whiT,
                                                         f16* __restrict__ wloT) {
    __shared__ float tile[64][65];
    const int kb = blockIdx.x;      // 0..11
    const int nb = blockIdx.y;      // 0..255
    const int t  = threadIdx.x;
    const int col = t & 63;
    const int r4  = t >> 6;
#pragma unroll
    for (int p = 0; p < 16; ++p) {
        const int kr = p * 4 + r4;
        tile[kr][col] = W[(size_t)(kb * 64 + kr) * H_DIM + nb * 64 + col];
    }
    __syncthreads();
    const int n  = t >> 2;
    const int kq = (t & 3) * 16;
    f16x8 h0, h1, l0, l1;
#pragma unroll
    for (int j = 0; j < 8; ++j) {
        const float v0 = tile[kq + j][n];
        const f16 ha = (f16)v0; h0[j] = ha; l0[j] = (f16)(v0 - (float)ha);
        const float v1 = tile[kq + 8 + j][n];
        const f16 hb = (f16)v1; h1[j] = hb; l1[j] = (f16)(v1 - (float)hb);
    }
    const size_t base = (size_t)(nb * 64 + n) * D_IN + kb * 64 + kq;
    *(f16x8*)&whiT[base]     = h0;
    *(f16x8*)&whiT[base + 8] = h1;
    *(f16x8*)&wloT[base]     = l0;
    *(f16x8*)&wloT[base + 8] = l1;
}

// ---------------- encode GEMM (R5-proven loop) + fused candidate extraction ----------
#define STAGE(buf, kt) do {                                                        \
    const int ko_ = (kt) * BK;                                                     \
    _Pragma("unroll")                                                              \
    for (int q_ = 0; q_ < 4; ++q_)                                                 \
        gload_lds16(xhi + aoff[q_] + ko_, sA + (buf) * 16384 + q_ * 4096 + tid * 8);\
    _Pragma("unroll")                                                              \
    for (int q_ = 0; q_ < 4; ++q_)                                                 \
        gload_lds16(whiT + boff[q_] + ko_, sB + (buf) * 16384 + q_ * 4096 + tid * 8);\
} while (0)

__global__ __launch_bounds__(512, 2) void encode_gemm256(const f16* __restrict__ xhi,
                                                         const f16* __restrict__ whiT,
                                                         const float* __restrict__ b_enc,
                                                         const float* __restrict__ theta,
                                                         float* __restrict__ preact,
                                                         int* __restrict__ cig,
                                                         float* __restrict__ cvg,
                                                         int* __restrict__ cntg) {
    extern __shared__ __align__(16) f16 smem[];
    f16* sA = smem;            // 2 * 256 * 64 f16
    f16* sB = smem + 32768;    // 2 * 256 * 64 f16
    float* sTheta = (float*)(smem + 65536);   // 256 f32
    const int tid = threadIdx.x;
    const int bid = blockIdx.x;
    const int swz = (bid & 7) * 128 + (bid >> 3);   // XCD swizzle, nwg=1024 % 8 == 0
    const int m0 = (swz >> 6) * BM;                 // 16 m-blocks
    const int n0 = (swz & 63) * BN;                 // 64 n-blocks
    const int lane = tid & 63;
    const int wr = (tid >> 6) >> 2;                 // 0..1
    const int wc = (tid >> 6) & 3;                  // 0..3
    const int fr = lane & 15;
    const int fk = lane >> 4;
    const int sxk0 = ((fk)     ^ (fr & 7)) * 8;
    const int sxk1 = ((fk + 4) ^ (fr & 7)) * 8;

    if (tid < 256) sTheta[tid] = theta[m0 + tid];   // visible after first __syncthreads

    const int sw = ((tid & 7) ^ ((tid >> 3) & 7)) << 3;
    int aoff[4], boff[4];
#pragma unroll
    for (int q = 0; q < 4; ++q) {
        const int p = q * 64 + (tid >> 3);
        aoff[q] = (m0 + p) * D_IN + sw;
        boff[q] = (n0 + p) * D_IN + sw;
    }

    floatx4 acc[8][4];
    const floatx4 zero = {0.f, 0.f, 0.f, 0.f};
#pragma unroll
    for (int i = 0; i < 8; ++i)
#pragma unroll
        for (int j = 0; j < 4; ++j) acc[i][j] = zero;

    STAGE(0, 0);
    for (int t = 0; t < NKT; ++t) {
        __syncthreads();
        if (t + 1 < NKT) STAGE((t + 1) & 1, t + 1);
        const int bufo = (t & 1) * 16384;
#pragma unroll
        for (int ks = 0; ks < 2; ++ks) {
            const int sx = ks ? sxk1 : sxk0;
            f16x8 af[8], bf[4];
#pragma unroll
            for (int mi = 0; mi < 8; ++mi)
                af[mi] = *(const f16x8*)(sA + bufo + (wr * 128 + mi * 16 + fr) * 64 + sx);
#pragma unroll
            for (int ni = 0; ni < 4; ++ni)
                bf[ni] = *(const f16x8*)(sB + bufo + (wc * 64 + ni * 16 + fr) * 64 + sx);
#pragma unroll
            for (int mi = 0; mi < 8; ++mi)
#pragma unroll
                for (int ni = 0; ni < 4; ++ni)
                    acc[mi][ni] = __builtin_amdgcn_mfma_f32_16x16x32_f16(
                        af[mi], bf[ni], acc[mi][ni], 0, 0, 0);
        }
    }

    // epilogue: store preact + append candidates (v > theta_row)
#pragma unroll
    for (int ni = 0; ni < 4; ++ni) {
        const int col = n0 + wc * 64 + ni * 16 + fr;
        const float bias = b_enc[col];
#pragma unroll
        for (int mi = 0; mi < 8; ++mi) {
            const int rloc = wr * 128 + mi * 16 + fk * 4;
            float* p = preact + (size_t)(m0 + rloc) * H_DIM + col;
#pragma unroll
            for (int j = 0; j < 4; ++j) {
                const float v = acc[mi][ni][j] + bias;
                p[(size_t)j * H_DIM] = v;
                if (v > sTheta[rloc + j]) {
                    const int row = m0 + rloc + j;
                    const int pos = atomicAdd(&cntg[row], 1);
                    if (pos < NCAP) {
                        cig[(size_t)row * NCAP + pos] = col;
                        cvg[(size_t)row * NCAP + pos] = v;
                    }
                }
            }
        }
    }
}

// ---------------- fused tail: window refine + hidden write + decode ----------------
// Candidates (idx, approx) come from encode. Find 32nd-largest approx v*, exact-
// recompute only approx >= v* - WIN (superset of exact top-32 since per-element
// |approx-exact| <= 0.0078 measured, WIN/2 = 0.02 margin), exact (val,idx) rank.
// Selection is order-invariant -> deterministic under atomic append order.
__global__ __launch_bounds__(256) void fused_tail(const float* __restrict__ x,
                                                  const f16* __restrict__ whiT,
                                                  const f16* __restrict__ wloT,
                                                  const float* __restrict__ b_enc,
                                                  const int* __restrict__ cig,
                                                  const float* __restrict__ cvg,
                                                  const int* __restrict__ cntg,
                                                  const float* __restrict__ Wdec,
                                                  const float* __restrict__ bdec,
                                                  float* __restrict__ hidden,
                                                  float* __restrict__ out) {
    const int row  = blockIdx.x;
    const int t    = threadIdx.x;
    const int lane = t & 63;
    const int wave = t >> 6;

    __shared__ float xr[D_IN];
    __shared__ int   ci[NCAP];
    __shared__ float ca[NCAP];
    __shared__ int   wi[NCAP];
    __shared__ float wv[NCAP];
    __shared__ float selv[TOPK_N];
    __shared__ int   seli[TOPK_N];
    __shared__ unsigned wcnt_s;
    __shared__ float vstar_s;

    const int cnt_raw = cntg[row];
    const int cnt = cnt_raw < NCAP ? cnt_raw : NCAP;
#pragma unroll
    for (int j = 0; j < 3; ++j)
        xr[t + 256 * j] = x[(size_t)row * D_IN + t + 256 * j];
    if (t < NCAP && t < cnt) {
        ci[t] = cig[(size_t)row * NCAP + t];
        ca[t] = cvg[(size_t)row * NCAP + t];
    }
    if (t < TOPK_N) { selv[t] = -3.0e38f; seli[t] = -1; }
    if (t == 0) { wcnt_s = 0u; vstar_s = -3.0e38f; }
    __syncthreads();

    // 32nd-largest approx (unique rank via (val desc, idx asc))
    if (cnt >= TOPK_N && t < cnt) {
        const float vi = ca[t];
        const int   ii = ci[t];
        int rank = 0;
        for (int j = 0; j < cnt; ++j) {
            const float vj = ca[j];
            rank += (vj > vi) || (vj == vi && ci[j] < ii);
        }
        if (rank == TOPK_N - 1) vstar_s = vi;
    }
    __syncthreads();
    const float wlo = vstar_s - WIN;   // cnt<32: -inf -> keep all

    if (t < cnt && ca[t] >= wlo) {
        const unsigned p = atomicAdd(&wcnt_s, 1u);
        wi[p] = ci[t];                 // p < NCAP always (wcnt <= cnt <= NCAP)
    }
    __syncthreads();
    const int wcnt = (int)wcnt_s;

    // exact fp32 dots for window candidates (R5 refine inner loop)
    for (int c = wave; c < wcnt; c += 4) {
        const int n = wi[c];
        float sum = 0.f;
        const f16* wh = whiT + (size_t)n * D_IN;
        const f16* wl = wloT + (size_t)n * D_IN;
#pragma unroll
        for (int j = 0; j < 12; ++j) {
            const int k = lane + 64 * j;
            sum += xr[k] * ((float)wh[k] + (float)wl[k]);
        }
#pragma unroll
        for (int off = 32; off > 0; off >>= 1) sum += __shfl_down(sum, off);
        if (lane == 0) wv[c] = sum + b_enc[n];
    }
    __syncthreads();

    // exact rank among window
    if (t < wcnt) {
        const float vi = wv[t];
        const int   ii = wi[t];
        int rank = 0;
        for (int j = 0; j < wcnt; ++j) {
            const float vj = wv[j];
            rank += (vj > vi) || (vj == vi && wi[j] < ii);
        }
        if (rank < TOPK_N) { selv[rank] = vi; seli[rank] = ii; }
    }
    __syncthreads();

    // zero hidden row, scatter top-32
    float* hrow = hidden + (size_t)row * H_DIM;
    const float4 z = {0.f, 0.f, 0.f, 0.f};
#pragma unroll
    for (int i = 0; i < 16; ++i) ((float4*)hrow)[t + 256 * i] = z;
    __syncthreads();
    if (t < TOPK_N) {
        const int n = seli[t];
        float v = selv[t];
        v = (n >= 0) ? fmaxf(v, 0.f) : 0.f;
        if (v > 0.f) hrow[n] = v;
    }

    // decode (R9-proven)
    float a0 = 0.f, a1 = 0.f, a2 = 0.f;
#pragma unroll 4
    for (int j = 0; j < TOPK_N; ++j) {
        const int n = seli[j];
        const float v = (n >= 0) ? fmaxf(selv[j], 0.f) : 0.f;
        const float* wr = Wdec + (size_t)(n >= 0 ? n : 0) * D_IN;
        a0 += v * wr[t];
        a1 += v * wr[t + 256];
        a2 += v * wr[t + 512];
    }
    float* orow = out + (size_t)row * D_IN;
    orow[t]       = fmaxf(a0 + bdec[t], 0.f);
    orow[t + 256] = fmaxf(a1 + bdec[t + 256], 0.f);
    orow[t + 512] = fmaxf(a2 + bdec[t + 512], 0.f);
}

extern "C" void kernel_launch(void* const* d_in, const int* in_sizes, int n_in,
                              void* d_out, int out_size, void* d_ws, size_t ws_size,
                              hipStream_t stream) {
    const float* x     = (const float*)d_in[0];
    const float* W_enc = (const float*)d_in[1];
    const float* b_enc = (const float*)d_in[2];
    const float* W_dec = (const float*)d_in[3];
    const float* b_dec = (const float*)d_in[4];

    float* out    = (float*)d_out;
    float* hidden = out + (size_t)B_ROWS * D_IN;
    float* preact = hidden + (size_t)B_ROWS * H_DIM;

    uint8_t* ws = (uint8_t*)d_ws;
    size_t off = 0;
    f16* xhi  = (f16*)(ws + off); off += (size_t)B_ROWS * D_IN * 2;
    f16* whiT = (f16*)(ws + off); off += (size_t)H_DIM * D_IN * 2;
    f16* wloT = (f16*)(ws + off); off += (size_t)H_DIM * D_IN * 2;
    float* theta = (float*)(ws + off); off += (size_t)B_ROWS * 4;
    int*   cntg  = (int*)(ws + off);   off += (size_t)B_ROWS * 4;
    int*   cig   = (int*)(ws + off);   off += (size_t)B_ROWS * NCAP * 4;
    float* cvg   = (float*)(ws + off); off += (size_t)B_ROWS * NCAP * 4;
    if (off > ws_size) return;  // insufficient workspace -> fail visibly

    hipFuncSetAttribute(reinterpret_cast<const void*>(encode_gemm256),
                        hipFuncAttributeMaxDynamicSharedMemorySize, 132096);

    split_x_theta<<<B_ROWS, 192, 0, stream>>>(x, xhi, theta, cntg);
    dim3 gw(D_IN / 64, H_DIM / 64);
    split_transpose_w<<<gw, 256, 0, stream>>>(W_enc, whiT, wloT);
    encode_gemm256<<<(B_ROWS / BM) * (H_DIM / BN), 512, 132096, stream>>>(
        xhi, whiT, b_enc, theta, preact, cig, cvg, cntg);
    fused_tail<<<B_ROWS, 256, 0, stream>>>(x, whiT, wloT, b_enc, cig, cvg, cntg,
                                           W_dec, b_dec, hidden, out);
}

// Round 11
// 419.194 us; speedup vs baseline: 1.0106x; 1.0106x over previous
//
#include <hip/hip_runtime.h>
#include <stdint.h>

typedef _Float16 f16;
typedef _Float16 f16x4 __attribute__((ext_vector_type(4)));
typedef _Float16 f16x8 __attribute__((ext_vector_type(8)));
typedef float floatx4 __attribute__((ext_vector_type(4)));

#define B_ROWS 4096
#define D_IN   768
#define H_DIM  16384
#define TOPK_N 32
#define NCAP   256           // per-row candidate cap (mean ~117, 13 sigma to cap)
#define THETA_C 0.0264565f   // 2.45 * sqrt(2/(768+16384))
#define WIN     0.04f        // exact-recompute window below approx rank-32

#define BM 256
#define BN 256
#define BK 64
#define NKT (D_IN / BK)   // 12 K-tiles

typedef __attribute__((address_space(1))) const unsigned int g_uint;
typedef __attribute__((address_space(3))) unsigned int l_uint;

__device__ __forceinline__ void gload_lds16(const void* g, void* l) {
    __builtin_amdgcn_global_load_lds((g_uint*)(uintptr_t)g,
                                     (l_uint*)(uint32_t)(uintptr_t)l,
                                     16, 0, 0);
}

// ---------------- split x -> f16 + per-row theta (R10-proven) ----------------
__global__ __launch_bounds__(192) void split_x_theta(const float* __restrict__ x,
                                                     f16* __restrict__ xhi,
                                                     float* __restrict__ theta) {
    const int row = blockIdx.x;
    const int t   = threadIdx.x;          // 0..191, one float4 each
    const float4 q = ((const float4*)(x + (size_t)row * D_IN))[t];
    f16x4 h;
    h[0] = (f16)q.x; h[1] = (f16)q.y; h[2] = (f16)q.z; h[3] = (f16)q.w;
    ((f16x4*)xhi)[(size_t)row * (D_IN / 4) + t] = h;
    float ss = q.x * q.x + q.y * q.y + q.z * q.z + q.w * q.w;
#pragma unroll
    for (int off = 32; off > 0; off >>= 1) ss += __shfl_down(ss, off);
    __shared__ float swave[3];
    if ((t & 63) == 0) swave[t >> 6] = ss;
    __syncthreads();
    if (t == 0) {
        const float tot = swave[0] + swave[1] + swave[2];
        theta[row] = THETA_C * sqrtf(tot);
    }
}

// ---------------- transpose + hi/lo split of W_enc (R5-verbatim) ----------------
__global__ __launch_bounds__(256) void split_transpose_w(const float* __restrict__ W,
                                                         f16* __restrict__ whiT,
                                                         f16* __restrict__ wloT) {
    __shared__ float tile[64][65];
    const int kb = blockIdx.x;      // 0..11
    const int nb = blockIdx.y;      // 0..255
    const int t  = threadIdx.x;
    const int col = t & 63;
    const int r4  = t >> 6;
#pragma unroll
    for (int p = 0; p < 16; ++p) {
        const int kr = p * 4 + r4;
        tile[kr][col] = W[(size_t)(kb * 64 + kr) * H_DIM + nb * 64 + col];
    }
    __syncthreads();
    const int n  = t >> 2;
    const int kq = (t & 3) * 16;
    f16x8 h0, h1, l0, l1;
#pragma unroll
    for (int j = 0; j < 8; ++j) {
        const float v0 = tile[kq + j][n];
        const f16 ha = (f16)v0; h0[j] = ha; l0[j] = (f16)(v0 - (float)ha);
        const float v1 = tile[kq + 8 + j][n];
        const f16 hb = (f16)v1; h1[j] = hb; l1[j] = (f16)(v1 - (float)hb);
    }
    const size_t base = (size_t)(nb * 64 + n) * D_IN + kb * 64 + kq;
    *(f16x8*)&whiT[base]     = h0;
    *(f16x8*)&whiT[base + 8] = h1;
    *(f16x8*)&wloT[base]     = l0;
    *(f16x8*)&wloT[base + 8] = l1;
}

// ---------------- encode GEMM: 256x256, BK=64, classic dbuf (R5-verbatim) ----------
#define STAGE(buf, kt) do {                                                        \
    const int ko_ = (kt) * BK;                                                     \
    _Pragma("unroll")                                                              \
    for (int q_ = 0; q_ < 4; ++q_)                                                 \
        gload_lds16(xhi + aoff[q_] + ko_, sA + (buf) * 16384 + q_ * 4096 + tid * 8);\
    _Pragma("unroll")                                                              \
    for (int q_ = 0; q_ < 4; ++q_)                                                 \
        gload_lds16(whiT + boff[q_] + ko_, sB + (buf) * 16384 + q_ * 4096 + tid * 8);\
} while (0)

__global__ __launch_bounds__(512, 2) void encode_gemm256(const f16* __restrict__ xhi,
                                                         const f16* __restrict__ whiT,
                                                         const float* __restrict__ b_enc,
                                                         float* __restrict__ preact) {
    extern __shared__ __align__(16) f16 smem[];
    f16* sA = smem;            // 2 * 256 * 64 f16
    f16* sB = smem + 32768;    // 2 * 256 * 64 f16
    const int tid = threadIdx.x;
    const int bid = blockIdx.x;
    const int swz = (bid & 7) * 128 + (bid >> 3);   // XCD swizzle, nwg=1024 % 8 == 0
    const int m0 = (swz >> 6) * BM;                 // 16 m-blocks
    const int n0 = (swz & 63) * BN;                 // 64 n-blocks
    const int lane = tid & 63;
    const int wr = (tid >> 6) >> 2;                 // 0..1
    const int wc = (tid >> 6) & 3;                  // 0..3
    const int fr = lane & 15;
    const int fk = lane >> 4;
    const int sxk0 = ((fk)     ^ (fr & 7)) * 8;
    const int sxk1 = ((fk + 4) ^ (fr & 7)) * 8;

    const int sw = ((tid & 7) ^ ((tid >> 3) & 7)) << 3;
    int aoff[4], boff[4];
#pragma unroll
    for (int q = 0; q < 4; ++q) {
        const int p = q * 64 + (tid >> 3);
        aoff[q] = (m0 + p) * D_IN + sw;
        boff[q] = (n0 + p) * D_IN + sw;
    }

    floatx4 acc[8][4];
    const floatx4 zero = {0.f, 0.f, 0.f, 0.f};
#pragma unroll
    for (int i = 0; i < 8; ++i)
#pragma unroll
        for (int j = 0; j < 4; ++j) acc[i][j] = zero;

    STAGE(0, 0);
    for (int t = 0; t < NKT; ++t) {
        __syncthreads();
        if (t + 1 < NKT) STAGE((t + 1) & 1, t + 1);
        const int bufo = (t & 1) * 16384;
#pragma unroll
        for (int ks = 0; ks < 2; ++ks) {
            const int sx = ks ? sxk1 : sxk0;
            f16x8 af[8], bf[4];
#pragma unroll
            for (int mi = 0; mi < 8; ++mi)
                af[mi] = *(const f16x8*)(sA + bufo + (wr * 128 + mi * 16 + fr) * 64 + sx);
#pragma unroll
            for (int ni = 0; ni < 4; ++ni)
                bf[ni] = *(const f16x8*)(sB + bufo + (wc * 64 + ni * 16 + fr) * 64 + sx);
#pragma unroll
            for (int mi = 0; mi < 8; ++mi)
#pragma unroll
                for (int ni = 0; ni < 4; ++ni)
                    acc[mi][ni] = __builtin_amdgcn_mfma_f32_16x16x32_f16(
                        af[mi], bf[ni], acc[mi][ni], 0, 0, 0);
        }
    }

#pragma unroll
    for (int ni = 0; ni < 4; ++ni) {
        const int col = n0 + wc * 64 + ni * 16 + fr;
        const float bias = b_enc[col];
#pragma unroll
        for (int mi = 0; mi < 8; ++mi) {
            const int row = m0 + wr * 128 + mi * 16 + fk * 4;
            float* p = preact + (size_t)row * H_DIM + col;
#pragma unroll
            for (int j = 0; j < 4; ++j)
                p[(size_t)j * H_DIM] = acc[mi][ni][j] + bias;
        }
    }
}

// ---------------- candidate selection: theta threshold, single pass ----------------
// Collect (idx, approx v) with v > theta_row. E[cnt]=117; true top-32 always above
// theta (0.43 sigma margin) and below cap (13 sigma) -- R10-validated.
__global__ __launch_bounds__(256) void topk_theta(const float* __restrict__ preact,
                                                  const float* __restrict__ theta,
                                                  int* __restrict__ cand,
                                                  float* __restrict__ candv,
                                                  int* __restrict__ ccnt) {
    const int row = blockIdx.x;
    const int t   = threadIdx.x;
    const float th = theta[row];
    const float* pr = preact + (size_t)row * H_DIM;

    __shared__ int   li[NCAP];
    __shared__ float lv[NCAP];
    __shared__ unsigned cnt_s;
    if (t == 0) cnt_s = 0u;
    __syncthreads();

#pragma unroll
    for (int i = 0; i < 16; ++i) {
        const float4 q = ((const float4*)pr)[t + 256 * i];
        const int gbase = 4 * t + 1024 * i;
#pragma unroll
        for (int j = 0; j < 4; ++j) {
            const float v = (j == 0) ? q.x : (j == 1) ? q.y : (j == 2) ? q.z : q.w;
            if (v > th) {
                const unsigned p = atomicAdd(&cnt_s, 1u);
                if (p < NCAP) { li[p] = gbase + j; lv[p] = v; }
            }
        }
    }
    __syncthreads();
    const int cnt = (int)(cnt_s < NCAP ? cnt_s : NCAP);
    if (t < cnt) {
        cand[(size_t)row * NCAP + t]  = li[t];
        candv[(size_t)row * NCAP + t] = lv[t];
    }
    if (t == 0) ccnt[row] = cnt;
}

// ---------------- exact fp32 window refinement + hidden write (R10 tail logic) ----
__global__ __launch_bounds__(256) void refine_kernel(const float* __restrict__ x,
                                                     const f16* __restrict__ whiT,
                                                     const f16* __restrict__ wloT,
                                                     const float* __restrict__ b_enc,
                                                     const int* __restrict__ cand,
                                                     const float* __restrict__ candv,
                                                     const int* __restrict__ ccnt,
                                                     float* __restrict__ hidden,
                                                     float* __restrict__ topv,
                                                     int* __restrict__ topi) {
    const int row  = blockIdx.x;
    const int t    = threadIdx.x;
    const int lane = t & 63;
    const int wave = t >> 6;
    __shared__ float xr[D_IN];
    __shared__ int   ci[NCAP];
    __shared__ float ca[NCAP];
    __shared__ int   wi[NCAP];
    __shared__ float wv[NCAP];
    __shared__ float selv[TOPK_N];
    __shared__ int   seli[TOPK_N];
    __shared__ unsigned wcnt_s;
    __shared__ float vstar_s;

    const int cnt = ccnt[row];
    if (t < NCAP && t < cnt) {
        ci[t] = cand[(size_t)row * NCAP + t];
        ca[t] = candv[(size_t)row * NCAP + t];
    }
    if (t < TOPK_N) { selv[t] = -3.0e38f; seli[t] = -1; }
    if (t == 0) { wcnt_s = 0u; vstar_s = -3.0e38f; }
#pragma unroll
    for (int j = 0; j < 3; ++j)
        xr[t + 256 * j] = x[(size_t)row * D_IN + t + 256 * j];
    __syncthreads();

    // 32nd-largest approx (unique rank via (val desc, idx asc))
    if (cnt >= TOPK_N && t < cnt) {
        const float vi = ca[t];
        const int   ii = ci[t];
        int rank = 0;
        for (int j = 0; j < cnt; ++j) {
            const float vj = ca[j];
            rank += (vj > vi) || (vj == vi && ci[j] < ii);
        }
        if (rank == TOPK_N - 1) vstar_s = vi;
    }
    __syncthreads();
    const float wlo = vstar_s - WIN;   // cnt<32: -inf -> keep all

    if (t < cnt && ca[t] >= wlo) {
        const unsigned p = atomicAdd(&wcnt_s, 1u);
        wi[p] = ci[t];
    }
    __syncthreads();
    const int wcnt = (int)wcnt_s;

    // exact fp32 dots for window candidates (R5 refine inner loop, verbatim)
    for (int c = wave; c < wcnt; c += 4) {
        const int n = wi[c];
        float sum = 0.f;
        const f16* wh = whiT + (size_t)n * D_IN;
        const f16* wl = wloT + (size_t)n * D_IN;
#pragma unroll
        for (int j = 0; j < 12; ++j) {
            const int k = lane + 64 * j;
            sum += xr[k] * ((float)wh[k] + (float)wl[k]);
        }
#pragma unroll
        for (int off = 32; off > 0; off >>= 1) sum += __shfl_down(sum, off);
        if (lane == 0) wv[c] = sum + b_enc[n];
    }
    __syncthreads();

    // exact rank among window (same comparator as R5)
    if (t < wcnt) {
        const float vi = wv[t];
        const int   ii = wi[t];
        int rank = 0;
        for (int j = 0; j < wcnt; ++j) {
            const float vj = wv[j];
            rank += (vj > vi) || (vj == vi && wi[j] < ii);
        }
        if (rank < TOPK_N) { selv[rank] = vi; seli[rank] = ii; }
    }
    __syncthreads();

    float* hrow = hidden + (size_t)row * H_DIM;
    const float4 z = {0.f, 0.f, 0.f, 0.f};
#pragma unroll
    for (int i = 0; i < 16; ++i) ((float4*)hrow)[t + 256 * i] = z;
    __syncthreads();
    if (t < TOPK_N) {
        const int n = seli[t];
        float v = selv[t];
        v = (n >= 0) ? fmaxf(v, 0.f) : 0.f;
        topv[row * TOPK_N + t] = v;
        topi[row * TOPK_N + t] = (n >= 0) ? n : 0;
        if (v > 0.f) hrow[n] = v;
    }
}

// ---------------- sparse decode (R5-verbatim) ----------------
__global__ __launch_bounds__(256) void decode_kernel(const float* __restrict__ topv,
                                                     const int* __restrict__ topi,
                                                     const float* __restrict__ Wdec,
                                                     const float* __restrict__ bdec,
                                                     float* __restrict__ out) {
    const int row = blockIdx.x;
    const int t   = threadIdx.x;
    __shared__ float sv[TOPK_N];
    __shared__ int   si[TOPK_N];
    if (t < TOPK_N) { sv[t] = topv[row * TOPK_N + t]; si[t] = topi[row * TOPK_N + t]; }
    __syncthreads();
    float a0 = 0.f, a1 = 0.f, a2 = 0.f;
#pragma unroll 4
    for (int j = 0; j < TOPK_N; ++j) {
        const float v = sv[j];
        const float* wr = Wdec + (size_t)si[j] * D_IN;
        a0 += v * wr[t];
        a1 += v * wr[t + 256];
        a2 += v * wr[t + 512];
    }
    float* orow = out + (size_t)row * D_IN;
    orow[t]       = fmaxf(a0 + bdec[t], 0.f);
    orow[t + 256] = fmaxf(a1 + bdec[t + 256], 0.f);
    orow[t + 512] = fmaxf(a2 + bdec[t + 512], 0.f);
}

extern "C" void kernel_launch(void* const* d_in, const int* in_sizes, int n_in,
                              void* d_out, int out_size, void* d_ws, size_t ws_size,
                              hipStream_t stream) {
    const float* x     = (const float*)d_in[0];
    const float* W_enc = (const float*)d_in[1];
    const float* b_enc = (const float*)d_in[2];
    const float* W_dec = (const float*)d_in[3];
    const float* b_dec = (const float*)d_in[4];

    float* out    = (float*)d_out;
    float* hidden = out + (size_t)B_ROWS * D_IN;
    float* preact = hidden + (size_t)B_ROWS * H_DIM;

    uint8_t* ws = (uint8_t*)d_ws;
    size_t off = 0;
    f16* xhi  = (f16*)(ws + off); off += (size_t)B_ROWS * D_IN * 2;
    f16* whiT = (f16*)(ws + off); off += (size_t)H_DIM * D_IN * 2;
    f16* wloT = (f16*)(ws + off); off += (size_t)H_DIM * D_IN * 2;
    float* theta = (float*)(ws + off); off += (size_t)B_ROWS * 4;
    int*   cand  = (int*)(ws + off);   off += (size_t)B_ROWS * NCAP * 4;
    float* candv = (float*)(ws + off); off += (size_t)B_ROWS * NCAP * 4;
    int*   ccnt  = (int*)(ws + off);   off += (size_t)B_ROWS * 4;
    float* topv  = (float*)(ws + off); off += (size_t)B_ROWS * TOPK_N * 4;
    int*   topi  = (int*)(ws + off);   off += (size_t)B_ROWS * TOPK_N * 4;
    if (off > ws_size) return;  // insufficient workspace -> fail visibly

    hipFuncSetAttribute(reinterpret_cast<const void*>(encode_gemm256),
                        hipFuncAttributeMaxDynamicSharedMemorySize, 131072);

    split_x_theta<<<B_ROWS, 192, 0, stream>>>(x, xhi, theta);
    dim3 gw(D_IN / 64, H_DIM / 64);
    split_transpose_w<<<gw, 256, 0, stream>>>(W_enc, whiT, wloT);
    encode_gemm256<<<(B_ROWS / BM) * (H_DIM / BN), 512, 131072, stream>>>(xhi, whiT, b_enc, preact);
    topk_theta<<<B_ROWS, 256, 0, stream>>>(preact, theta, cand, candv, ccnt);
    refine_kernel<<<B_ROWS, 256, 0, stream>>>(x, whiT, wloT, b_enc, cand, candv, ccnt,
                                              hidden, topv, topi);
    decode_kernel<<<B_ROWS, 256, 0, stream>>>(topv, topi, W_dec, b_dec, out);
}

// Round 12
// 388.584 us; speedup vs baseline: 1.0902x; 1.0788x over previous
//
#include <hip/hip_runtime.h>
#include <stdint.h>

typedef _Float16 f16;
typedef _Float16 f16x4 __attribute__((ext_vector_type(4)));
typedef _Float16 f16x8 __attribute__((ext_vector_type(8)));
typedef float floatx4 __attribute__((ext_vector_type(4)));

#define B_ROWS 4096
#define D_IN   768
#define H_DIM  16384
#define TOPK_N 32
#define NC     40    // target candidate count (superset of exact top-32)
#define NCAP   192   // hard cap on candidates per row

#define BM 256
#define BN 256
#define BK 64
#define NKT (D_IN / BK)   // 12 K-tiles

typedef __attribute__((address_space(1))) const unsigned int g_uint;
typedef __attribute__((address_space(3))) unsigned int l_uint;

__device__ __forceinline__ void gload_lds16(const void* g, void* l) {
    __builtin_amdgcn_global_load_lds((g_uint*)(uintptr_t)g,
                                     (l_uint*)(uint32_t)(uintptr_t)l,
                                     16, 0, 0);
}

// ---------------- fused prep: split_x (blocks 0..3071) + transpose W (3072..6143) ----
// Both bodies are R5-verbatim; uniform branch on blockIdx.x; independent regions.
__global__ __launch_bounds__(256) void prep_kernel(const float* __restrict__ x,
                                                   f16* __restrict__ xhi,
                                                   const float* __restrict__ W,
                                                   f16* __restrict__ whiT,
                                                   f16* __restrict__ wloT) {
    __shared__ float tile[64][65];
    const int t = threadIdx.x;
    if (blockIdx.x < 3072) {
        // ---- split_x: x fp32 -> f16 (R5-verbatim body) ----
        const int i = blockIdx.x * 256 + t;
        const float4 q = ((const float4*)x)[i];
        f16x4 h;
        h[0] = (f16)q.x; h[1] = (f16)q.y; h[2] = (f16)q.z; h[3] = (f16)q.w;
        ((f16x4*)xhi)[i] = h;
        return;
    }
    // ---- split_transpose_w (R5-verbatim body) ----
    const int linear = blockIdx.x - 3072;
    const int nb = linear / 12;     // 0..255
    const int kb = linear - nb * 12; // 0..11
    const int col = t & 63;
    const int r4  = t >> 6;
#pragma unroll
    for (int p = 0; p < 16; ++p) {
        const int kr = p * 4 + r4;
        tile[kr][col] = W[(size_t)(kb * 64 + kr) * H_DIM + nb * 64 + col];
    }
    __syncthreads();
    const int n  = t >> 2;
    const int kq = (t & 3) * 16;
    f16x8 h0, h1, l0, l1;
#pragma unroll
    for (int j = 0; j < 8; ++j) {
        const float v0 = tile[kq + j][n];
        const f16 ha = (f16)v0; h0[j] = ha; l0[j] = (f16)(v0 - (float)ha);
        const float v1 = tile[kq + 8 + j][n];
        const f16 hb = (f16)v1; h1[j] = hb; l1[j] = (f16)(v1 - (float)hb);
    }
    const size_t base = (size_t)(nb * 64 + n) * D_IN + kb * 64 + kq;
    *(f16x8*)&whiT[base]     = h0;
    *(f16x8*)&whiT[base + 8] = h1;
    *(f16x8*)&wloT[base]     = l0;
    *(f16x8*)&wloT[base + 8] = l1;
}

// ---------------- encode GEMM: 256x256, BK=64, classic dbuf (R5-verbatim) ----------
#define STAGE(buf, kt) do {                                                        \
    const int ko_ = (kt) * BK;                                                     \
    _Pragma("unroll")                                                              \
    for (int q_ = 0; q_ < 4; ++q_)                                                 \
        gload_lds16(xhi + aoff[q_] + ko_, sA + (buf) * 16384 + q_ * 4096 + tid * 8);\
    _Pragma("unroll")                                                              \
    for (int q_ = 0; q_ < 4; ++q_)                                                 \
        gload_lds16(whiT + boff[q_] + ko_, sB + (buf) * 16384 + q_ * 4096 + tid * 8);\
} while (0)

__global__ __launch_bounds__(512, 2) void encode_gemm256(const f16* __restrict__ xhi,
                                                         const f16* __restrict__ whiT,
                                                         const float* __restrict__ b_enc,
                                                         float* __restrict__ preact) {
    extern __shared__ __align__(16) f16 smem[];
    f16* sA = smem;            // 2 * 256 * 64 f16
    f16* sB = smem + 32768;    // 2 * 256 * 64 f16
    const int tid = threadIdx.x;
    const int bid = blockIdx.x;
    const int swz = (bid & 7) * 128 + (bid >> 3);   // XCD swizzle, nwg=1024 % 8 == 0
    const int m0 = (swz >> 6) * BM;                 // 16 m-blocks
    const int n0 = (swz & 63) * BN;                 // 64 n-blocks
    const int lane = tid & 63;
    const int wr = (tid >> 6) >> 2;                 // 0..1
    const int wc = (tid >> 6) & 3;                  // 0..3
    const int fr = lane & 15;
    const int fk = lane >> 4;
    const int sxk0 = ((fk)     ^ (fr & 7)) * 8;
    const int sxk1 = ((fk + 4) ^ (fr & 7)) * 8;

    const int sw = ((tid & 7) ^ ((tid >> 3) & 7)) << 3;
    int aoff[4], boff[4];
#pragma unroll
    for (int q = 0; q < 4; ++q) {
        const int p = q * 64 + (tid >> 3);
        aoff[q] = (m0 + p) * D_IN + sw;
        boff[q] = (n0 + p) * D_IN + sw;
    }

    floatx4 acc[8][4];
    const floatx4 zero = {0.f, 0.f, 0.f, 0.f};
#pragma unroll
    for (int i = 0; i < 8; ++i)
#pragma unroll
        for (int j = 0; j < 4; ++j) acc[i][j] = zero;

    STAGE(0, 0);
    for (int t = 0; t < NKT; ++t) {
        __syncthreads();
        if (t + 1 < NKT) STAGE((t + 1) & 1, t + 1);
        const int bufo = (t & 1) * 16384;
#pragma unroll
        for (int ks = 0; ks < 2; ++ks) {
            const int sx = ks ? sxk1 : sxk0;
            f16x8 af[8], bf[4];
#pragma unroll
            for (int mi = 0; mi < 8; ++mi)
                af[mi] = *(const f16x8*)(sA + bufo + (wr * 128 + mi * 16 + fr) * 64 + sx);
#pragma unroll
            for (int ni = 0; ni < 4; ++ni)
                bf[ni] = *(const f16x8*)(sB + bufo + (wc * 64 + ni * 16 + fr) * 64 + sx);
#pragma unroll
            for (int mi = 0; mi < 8; ++mi)
#pragma unroll
                for (int ni = 0; ni < 4; ++ni)
                    acc[mi][ni] = __builtin_amdgcn_mfma_f32_16x16x32_f16(
                        af[mi], bf[ni], acc[mi][ni], 0, 0, 0);
        }
    }

#pragma unroll
    for (int ni = 0; ni < 4; ++ni) {
        const int col = n0 + wc * 64 + ni * 16 + fr;
        const float bias = b_enc[col];
#pragma unroll
        for (int mi = 0; mi < 8; ++mi) {
            const int row = m0 + wr * 128 + mi * 16 + fk * 4;
            float* p = preact + (size_t)row * H_DIM + col;
#pragma unroll
            for (int j = 0; j < 4; ++j)
                p[(size_t)j * H_DIM] = acc[mi][ni][j] + bias;
        }
    }
}

// ---------------- candidate selection: single-level linear-bin select (R5-verbatim) ----
__global__ __launch_bounds__(256) void topk_approx(const float* __restrict__ preact,
                                                   int* __restrict__ cand,
                                                   int* __restrict__ ccnt) {
    const int row = blockIdx.x;
    const int t   = threadIdx.x;
    const float* pr = preact + (size_t)row * H_DIM;
    float vr[64];
    float m = 0.f;
#pragma unroll
    for (int i = 0; i < 16; ++i) {
        const float4 q = ((const float4*)pr)[t + 256 * i];
        vr[4 * i + 0] = q.x; vr[4 * i + 1] = q.y;
        vr[4 * i + 2] = q.z; vr[4 * i + 3] = q.w;
        m = fmaxf(m, fmaxf(fmaxf(q.x, q.y), fmaxf(q.z, q.w)));
    }
#pragma unroll
    for (int off = 32; off > 0; off >>= 1) m = fmaxf(m, __shfl_down(m, off));

    __shared__ float wmax[4];
    __shared__ unsigned hist[256];
    __shared__ unsigned sbin_s, out_cnt;
    if ((t & 63) == 0) wmax[t >> 6] = m;
    hist[t] = 0u;
    if (t == 0) { sbin_s = 0u; out_cnt = 0u; }
    __syncthreads();
    const float M = fmaxf(fmaxf(wmax[0], wmax[1]), fmaxf(wmax[2], wmax[3]));
    int* crow = cand + row * NCAP;

    if (M > 0.f) {
        const float scale = 256.0f / M;
#pragma unroll
        for (int e = 0; e < 64; ++e) {
            const float v = vr[e];
            if (v > 0.f) {
                int b = (int)(v * scale); b = b > 255 ? 255 : b;
                atomicAdd(&hist[b], 1u);
            }
        }
        __syncthreads();
        unsigned sval = hist[t];
        for (int off = 1; off < 256; off <<= 1) {
            const unsigned add = (t + off < 256) ? hist[t + off] : 0u;
            __syncthreads();
            sval += add;
            hist[t] = sval;
            __syncthreads();
        }
        const unsigned above = (t < 255) ? hist[t + 1] : 0u;
        if (sval >= NC && above < NC) sbin_s = (unsigned)t;
        __syncthreads();
        const int sbin = (int)sbin_s;
#pragma unroll
        for (int e = 0; e < 64; ++e) {
            const float v = vr[e];
            if (v > 0.f) {
                int b = (int)(v * scale); b = b > 255 ? 255 : b;
                if (b >= sbin) {
                    const unsigned p = atomicAdd(&out_cnt, 1u);
                    if (p < NCAP) crow[p] = 4 * t + 1024 * (e >> 2) + (e & 3);
                }
            }
        }
        __syncthreads();
    }
    if (t == 0) ccnt[row] = (int)(out_cnt < NCAP ? out_cnt : NCAP);
}

// ---------------- exact fp32 refinement of candidates + hidden write (R5-verbatim) ----
__global__ __launch_bounds__(256) void refine_kernel(const float* __restrict__ x,
                                                     const f16* __restrict__ whiT,
                                                     const f16* __restrict__ wloT,
                                                     const float* __restrict__ b_enc,
                                                     const int* __restrict__ cand,
                                                     const int* __restrict__ ccnt,
                                                     float* __restrict__ hidden,
                                                     float* __restrict__ topv,
                                                     int* __restrict__ topi) {
    const int row  = blockIdx.x;
    const int t    = threadIdx.x;
    const int lane = t & 63;
    const int wave = t >> 6;
    __shared__ float xr[D_IN];
    __shared__ float cv[NCAP];
    __shared__ int   ci[NCAP];
    __shared__ float selv[TOPK_N];
    __shared__ int   seli[TOPK_N];

    const int cnt = ccnt[row];
    if (t < NCAP) ci[t] = (t < cnt) ? cand[row * NCAP + t] : -1;
    if (t < TOPK_N) { selv[t] = -3.0e38f; seli[t] = -1; }
#pragma unroll
    for (int j = 0; j < 3; ++j)
        xr[t + 256 * j] = x[(size_t)row * D_IN + t + 256 * j];
    __syncthreads();

    for (int c = wave; c < cnt; c += 4) {
        const int n = ci[c];
        float sum = 0.f;
        const f16* wh = whiT + (size_t)n * D_IN;
        const f16* wl = wloT + (size_t)n * D_IN;
#pragma unroll
        for (int j = 0; j < 12; ++j) {
            const int k = lane + 64 * j;
            sum += xr[k] * ((float)wh[k] + (float)wl[k]);
        }
#pragma unroll
        for (int off = 32; off > 0; off >>= 1) sum += __shfl_down(sum, off);
        if (lane == 0) cv[c] = sum + b_enc[n];
    }
    __syncthreads();

    if (t < cnt) {
        const float vi = cv[t];
        const int   ii = ci[t];
        int rank = 0;
        for (int j = 0; j < cnt; ++j) {
            const float vj = cv[j];
            rank += (vj > vi) || (vj == vi && ci[j] < ii);
        }
        if (rank < TOPK_N) { selv[rank] = vi; seli[rank] = ii; }
    }
    __syncthreads();

    float* hrow = hidden + (size_t)row * H_DIM;
    const float4 z = {0.f, 0.f, 0.f, 0.f};
#pragma unroll
    for (int i = 0; i < 16; ++i) ((float4*)hrow)[t + 256 * i] = z;
    __syncthreads();
    if (t < TOPK_N) {
        const int n = seli[t];
        float v = selv[t];
        v = (n >= 0) ? fmaxf(v, 0.f) : 0.f;
        topv[row * TOPK_N + t] = v;
        topi[row * TOPK_N + t] = (n >= 0) ? n : 0;
        if (v > 0.f) hrow[n] = v;
    }
}

// ---------------- sparse decode (R5-verbatim) ----------------
__global__ __launch_bounds__(256) void decode_kernel(const float* __restrict__ topv,
                                                     const int* __restrict__ topi,
                                                     const float* __restrict__ Wdec,
                                                     const float* __restrict__ bdec,
                                                     float* __restrict__ out) {
    const int row = blockIdx.x;
    const int t   = threadIdx.x;
    __shared__ float sv[TOPK_N];
    __shared__ int   si[TOPK_N];
    if (t < TOPK_N) { sv[t] = topv[row * TOPK_N + t]; si[t] = topi[row * TOPK_N + t]; }
    __syncthreads();
    float a0 = 0.f, a1 = 0.f, a2 = 0.f;
#pragma unroll 4
    for (int j = 0; j < TOPK_N; ++j) {
        const float v = sv[j];
        const float* wr = Wdec + (size_t)si[j] * D_IN;
        a0 += v * wr[t];
        a1 += v * wr[t + 256];
        a2 += v * wr[t + 512];
    }
    float* orow = out + (size_t)row * D_IN;
    orow[t]       = fmaxf(a0 + bdec[t], 0.f);
    orow[t + 256] = fmaxf(a1 + bdec[t + 256], 0.f);
    orow[t + 512] = fmaxf(a2 + bdec[t + 512], 0.f);
}

extern "C" void kernel_launch(void* const* d_in, const int* in_sizes, int n_in,
                              void* d_out, int out_size, void* d_ws, size_t ws_size,
                              hipStream_t stream) {
    const float* x     = (const float*)d_in[0];
    const float* W_enc = (const float*)d_in[1];
    const float* b_enc = (const float*)d_in[2];
    const float* W_dec = (const float*)d_in[3];
    const float* b_dec = (const float*)d_in[4];

    float* out    = (float*)d_out;
    float* hidden = out + (size_t)B_ROWS * D_IN;
    float* preact = hidden + (size_t)B_ROWS * H_DIM;

    uint8_t* ws = (uint8_t*)d_ws;
    size_t off = 0;
    f16* xhi  = (f16*)(ws + off); off += (size_t)B_ROWS * D_IN * 2;
    f16* whiT = (f16*)(ws + off); off += (size_t)H_DIM * D_IN * 2;
    f16* wloT = (f16*)(ws + off); off += (size_t)H_DIM * D_IN * 2;
    int*   cand = (int*)(ws + off);  off += (size_t)B_ROWS * NCAP * 4;
    int*   ccnt = (int*)(ws + off);  off += (size_t)B_ROWS * 4;
    float* topv = (float*)(ws + off); off += (size_t)B_ROWS * TOPK_N * 4;
    int*   topi = (int*)(ws + off);  off += (size_t)B_ROWS * TOPK_N * 4;
    if (off > ws_size) return;  // insufficient workspace -> fail visibly

    hipFuncSetAttribute(reinterpret_cast<const void*>(encode_gemm256),
                        hipFuncAttributeMaxDynamicSharedMemorySize, 131072);

    prep_kernel<<<6144, 256, 0, stream>>>(x, xhi, W_enc, whiT, wloT);
    encode_gemm256<<<(B_ROWS / BM) * (H_DIM / BN), 512, 131072, stream>>>(xhi, whiT, b_enc, preact);
    topk_approx<<<B_ROWS, 256, 0, stream>>>(preact, cand, ccnt);
    refine_kernel<<<B_ROWS, 256, 0, stream>>>(x, whiT, wloT, b_enc, cand, ccnt, hidden, topv, topi);
    decode_kernel<<<B_ROWS, 256, 0, stream>>>(topv, topi, W_dec, b_dec, out);
}